// Round 3
// baseline (122.155 us; speedup 1.0000x reference)
//
#include <hip/hip_runtime.h>

#define NCLS 14
#define BATCH 2
#define NUM_BINS (BATCH * NCLS)
#define T_VOX 512                 // voxels per tile (per block)
#define CH2 (2 * NCLS)            // 28 staged channels (S then T)

// d_ws layout: float sums[NUM_BINS] | int counts[NUM_BINS]

__global__ void zero_bins_kernel(float* __restrict__ sums, int* __restrict__ counts) {
    int i = threadIdx.x;
    if (i < NUM_BINS) { sums[i] = 0.0f; counts[i] = 0; }
}

__device__ __forceinline__ void load_lds16(const void* g, void* l) {
    // async global->LDS, 16 B/lane: LDS dest = uniform base + lane*16
    __builtin_amdgcn_global_load_lds(
        (const __attribute__((address_space(1))) void*)g,
        (__attribute__((address_space(3))) void*)l, 16, 0, 0);
}

__global__ __launch_bounds__(256, 2) void kl_kernel(
        const float* __restrict__ S, const float* __restrict__ T,
        const int* __restrict__ gt,
        float* __restrict__ gsums, int* __restrict__ gcnts,
        int N /* voxels per batch image */) {
    __shared__ float lds[CH2 * T_VOX];     // [28][512] floats = 56 KB
    __shared__ float lsum[NUM_BINS];
    __shared__ int lcnt[NUM_BINS];

    const int tid = threadIdx.x;
    const int wave = tid >> 6;
    const int lane = tid & 63;
    const int tile = blockIdx.x;

    if (tid < NUM_BINS) { lsum[tid] = 0.0f; lcnt[tid] = 0; }

    // tile never straddles the batch boundary: N % T_VOX == 0
    const int g0 = tile * T_VOX;           // first global voxel of tile
    const int b = (g0 >= N) ? 1 : 0;
    const int n0 = g0 - b * N;

    const float* Sb = S + (size_t)b * NCLS * N + n0;
    const float* Tb = T + (size_t)b * NCLS * N + n0;

    // ---- stage 28 channels x 512 voxels: 56 x 1KB async loads, 14/wave ----
#pragma unroll
    for (int i = 0; i < 14; ++i) {
        int seg = wave * 14 + i;           // 0..55, wave-uniform
        int ch = seg >> 1;                 // 0..27
        int half = seg & 1;                // which 256-voxel half
        const float* src = ((ch < NCLS) ? Sb + (size_t)ch * N
                                        : Tb + (size_t)(ch - NCLS) * N)
                           + half * 256 + lane * 4;
        load_lds16(src, &lds[ch * T_VOX + half * 256]);
    }
    __syncthreads();   // drains vmcnt(0) before barrier

    // ---- compute: 2 voxels/thread from LDS ----
    const int v = tid * 2;
    float Zs0 = 0.f, Zt0 = 0.f, At0 = 0.f, As0 = 0.f;
    float Zs1 = 0.f, Zt1 = 0.f, At1 = 0.f, As1 = 0.f;
#pragma unroll
    for (int c = 0; c < NCLS; ++c) {
        float2 sv = *reinterpret_cast<const float2*>(&lds[c * T_VOX + v]);
        float2 tv = *reinterpret_cast<const float2*>(&lds[(NCLS + c) * T_VOX + v]);
        float et0 = __expf(tv.x), et1 = __expf(tv.y);
        Zt0 += et0;                  Zt1 += et1;
        At0 = fmaf(et0, tv.x, At0);  At1 = fmaf(et1, tv.y, At1);
        As0 = fmaf(et0, sv.x, As0);  As1 = fmaf(et1, sv.y, As1);
        Zs0 += __expf(sv.x);         Zs1 += __expf(sv.y);
    }
    float kl0 = (At0 - As0) / Zt0 - __logf(Zt0) + __logf(Zs0);
    float kl1 = (At1 - As1) / Zt1 - __logf(Zt1) + __logf(Zs1);

    int2 g2 = *reinterpret_cast<const int2*>(gt + (size_t)g0 + v);
    int c0 = min(max(g2.x, 0), NCLS - 1);
    int c1 = min(max(g2.y, 0), NCLS - 1);

    atomicAdd(&lsum[b * NCLS + c0], kl0);
    atomicAdd(&lcnt[b * NCLS + c0], 1);
    atomicAdd(&lsum[b * NCLS + c1], kl1);
    atomicAdd(&lcnt[b * NCLS + c1], 1);

    __syncthreads();
    if (tid < NUM_BINS) {
        atomicAdd(&gsums[tid], lsum[tid]);
        atomicAdd(&gcnts[tid], lcnt[tid]);
    }
}

__global__ void finalize_kernel(const float* __restrict__ sums,
                                const int* __restrict__ counts,
                                float* __restrict__ out) {
    if (threadIdx.x == 0) {
        float loss = 0.0f;
        for (int b = 0; b < BATCH; ++b) {
            for (int cls = 1; cls < NCLS; ++cls) {   // class 0 (background) excluded
                int idx = b * NCLS + cls;
                int cnt = counts[idx];
                if (cnt > 0) loss += sums[idx] / ((float)NCLS * (float)cnt);
            }
        }
        out[0] = loss;  // TAU^2 = 1, LOSS_WEIGHT = 1
    }
}

extern "C" void kernel_launch(void* const* d_in, const int* in_sizes, int n_in,
                              void* d_out, int out_size, void* d_ws, size_t ws_size,
                              hipStream_t stream) {
    const float* S = (const float*)d_in[0];
    const float* T = (const float*)d_in[1];
    const int* gt = (const int*)d_in[2];
    float* out = (float*)d_out;

    float* sums = (float*)d_ws;
    int* cnts = (int*)((char*)d_ws + NUM_BINS * sizeof(float));

    const int totalVox = in_sizes[2];       // B * 96^3 = 1,769,472 (= 3456 * 512)
    const int N = totalVox / BATCH;         // 884,736 (= 1728 * 512)

    const int grid = totalVox / T_VOX;      // 3456 tiles

    zero_bins_kernel<<<1, 64, 0, stream>>>(sums, cnts);
    kl_kernel<<<grid, 256, 0, stream>>>(S, T, gt, sums, cnts, N);
    finalize_kernel<<<1, 64, 0, stream>>>(sums, cnts, out);
}